// Round 1
// baseline (111.589 us; speedup 1.0000x reference)
//
#include <hip/hip_runtime.h>
#include <hip/hip_bf16.h>
#include <math.h>

#define FEAT 384
#define FFN  768
#define ZDIM 384
#define HID  192
#define BB   4
#define NN   128
#define BN   (BB*NN)   // 512 rows

// ---------------------------------------------------------------------------
// 3-stage pipeline (this round): cut per-block weight re-streaming 302->152MB
// and get 2 blocks/CU so barriers/epilogues overlap.
//  k_stage1: H = gelu(X@U_w + U_b), tiled 8 rows x 96 cols, 512 blocks (2/CU)
//            + tail blocks build WEG = [enc_w^T ; dec_w] as fp32 rows.
//  k_stage2: 256 z-path blocks (LN -> E=Z@enc_w, G=Z@dec_w^T -> diag/d0
//            partials via gelu identities, no dec GEMM / hid needed)
//          + 256 Y-path blocks (Y = xh@V_w, 8x96 tiles). One of each per CU.
//  k_combine: softmax-combine, reads 4 col-tile partials of d0/diag.
// ---------------------------------------------------------------------------

__device__ __forceinline__ float gelu_exact(float x) {
    return 0.5f * x * (1.0f + erff(x * 0.70710678118654752440f));
}

__device__ __forceinline__ float bflo(unsigned u) { return __uint_as_float(u << 16); }
__device__ __forceinline__ float bfhi(unsigned u) { return __uint_as_float(u & 0xFFFF0000u); }

template<bool F32>
__device__ __forceinline__ float ldg(const void* p, size_t i) {
    if constexpr (F32) return ((const float*)p)[i];
    return __uint_as_float(((unsigned)((const unsigned short*)p)[i]) << 16);
}
template<bool F32>
__device__ __forceinline__ void stg(void* p, size_t i, float v) {
    if constexpr (F32) ((float*)p)[i] = v;
    else ((__hip_bfloat16*)p)[i] = __float2bfloat16(v);
}

template<bool F32> struct V4;
template<> struct V4<true> {
    float4 a;
    __device__ __forceinline__ void load(const void* p, size_t off) {
        a = *(const float4*)((const float*)p + off);
    }
    __device__ __forceinline__ float g(int i) const { return (&a.x)[i]; }
};
template<> struct V4<false> {
    uint2 u;
    __device__ __forceinline__ void load(const void* p, size_t off) {
        u = *(const uint2*)((const unsigned short*)p + off);
    }
    __device__ __forceinline__ float g(int i) const {
        const unsigned w = (&u.x)[i >> 1];
        return (i & 1) ? bfhi(w) : bflo(w);
    }
};

template<bool F32>
__device__ __forceinline__ void load8(const void* p, size_t i, float o[8]) {
    if constexpr (F32) {
        const float4 a = *(const float4*)((const float*)p + i);
        const float4 b = *(const float4*)((const float*)p + i + 4);
        o[0]=a.x;o[1]=a.y;o[2]=a.z;o[3]=a.w;o[4]=b.x;o[5]=b.y;o[6]=b.z;o[7]=b.w;
    } else {
        const uint4 u = *(const uint4*)((const unsigned short*)p + i);
        o[0]=bflo(u.x);o[1]=bfhi(u.x);o[2]=bflo(u.y);o[3]=bfhi(u.y);
        o[4]=bflo(u.z);o[5]=bfhi(u.z);o[6]=bflo(u.w);o[7]=bfhi(u.w);
    }
}

__device__ __forceinline__ bool is_f32(const void* ln_w) {
    return ((const unsigned short*)ln_w)[0] == 0;
}

// ---- block reductions over 384 threads (6 wave64) ----
__device__ __forceinline__ float block_sum(float v, float* sm) {
    for (int o = 32; o > 0; o >>= 1) v += __shfl_down(v, o, 64);
    const int lane = threadIdx.x & 63, w = threadIdx.x >> 6;
    __syncthreads();
    if (lane == 0) sm[w] = v;
    __syncthreads();
    return sm[0] + sm[1] + sm[2] + sm[3] + sm[4] + sm[5];
}
__device__ __forceinline__ float block_max(float v, float* sm) {
    for (int o = 32; o > 0; o >>= 1) v = fmaxf(v, __shfl_down(v, o, 64));
    const int lane = threadIdx.x & 63, w = threadIdx.x >> 6;
    __syncthreads();
    if (lane == 0) sm[w] = v;
    __syncthreads();
    return fmaxf(fmaxf(fmaxf(sm[0], sm[1]), fmaxf(sm[2], sm[3])), fmaxf(sm[4], sm[5]));
}
// 16-wide block sum; sm must hold 96 floats
__device__ __forceinline__ void block_sum16(const float v[16], float* sm, float out[16]) {
    float tv[16];
    #pragma unroll
    for (int n = 0; n < 16; n++) tv[n] = v[n];
    for (int o = 32; o > 0; o >>= 1) {
        #pragma unroll
        for (int n = 0; n < 16; n++) tv[n] += __shfl_down(tv[n], o, 64);
    }
    const int lane = threadIdx.x & 63, w = threadIdx.x >> 6;
    __syncthreads();
    if (lane == 0) {
        #pragma unroll
        for (int n = 0; n < 16; n++) sm[n * 6 + w] = tv[n];
    }
    __syncthreads();
    #pragma unroll
    for (int n = 0; n < 16; n++)
        out[n] = sm[n*6] + sm[n*6+1] + sm[n*6+2] + sm[n*6+3] + sm[n*6+4] + sm[n*6+5];
}

// ---------------------------------------------------------------------------
// Tile GEMM: out[8 rows][96 cols] = xs(8x384, LDS) @ W[:, c0..c0+95], K=384.
// 384 threads: cg=t%24 (cols 4cg..4cg+3), kh=t/24 (k chunk [24kh,24kh+24)).
// Reduction: ALL kh write LDS partials, then all 384 threads reduce 2 slots
// each (fully parallel epilogue). part = 16*768 floats.
// Slot s (s=0,1): u = t + 384s -> (m=u/96, col=u%96).
// ---------------------------------------------------------------------------
template<bool F32>
__device__ __forceinline__ void tile_gemm_8x96(
    const void* __restrict__ W, int ldw, int c0,
    const float* __restrict__ xs, float* __restrict__ part, float out2[2])
{
    const int t = threadIdx.x;
    const int cg = t % 24, kh = t / 24;
    const int kb = kh * 24;
    const int cc = c0 + 4 * cg;
    float acc[8][4] = {};
    V4<F32> buf[2][8];
    #pragma unroll
    for (int j = 0; j < 8; j++) buf[0][j].load(W, (size_t)(kb + j) * ldw + cc);
    #pragma unroll
    for (int b = 0; b < 3; b++) {
        const int cur = b & 1;
        if (b < 2) {
            #pragma unroll
            for (int j = 0; j < 8; j++)
                buf[cur ^ 1][j].load(W, (size_t)(kb + 8 * (b + 1) + j) * ldw + cc);
        }
        #pragma unroll
        for (int m = 0; m < 8; m++) {
            const float4 x0 = *(const float4*)(xs + m * 384 + kb + 8 * b);
            const float4 x1 = *(const float4*)(xs + m * 384 + kb + 8 * b + 4);
            const float xv[8] = {x0.x,x0.y,x0.z,x0.w,x1.x,x1.y,x1.z,x1.w};
            #pragma unroll
            for (int j = 0; j < 8; j++) {
                #pragma unroll
                for (int i = 0; i < 4; i++)
                    acc[m][i] = fmaf(xv[j], buf[cur][j].g(i), acc[m][i]);
            }
        }
    }
    #pragma unroll
    for (int m = 0; m < 8; m++)
        *(float4*)(part + kh * 768 + m * 96 + 4 * cg) =
            make_float4(acc[m][0], acc[m][1], acc[m][2], acc[m][3]);
    __syncthreads();
    #pragma unroll
    for (int s = 0; s < 2; s++) {
        const int u = t + 384 * s;
        float v = 0.f;
        #pragma unroll
        for (int k2 = 0; k2 < 16; k2++) v += part[k2 * 768 + u];
        out2[s] = v;
    }
}

#define S_LDS 15360   // xs 3072 + part 12288 floats = 61.4 KB -> 2 blocks/CU

// ============ stage 1: U GEMM tiles + WEG build ============
template<bool F32>
__device__ void stage1_body(const void* __restrict__ x, const void* __restrict__ U_w,
                            const void* __restrict__ U_b,
                            const void* __restrict__ enc_w, const void* __restrict__ dec_w,
                            float* __restrict__ xh, float* __restrict__ z0,
                            float* __restrict__ WEG, float* S)
{
    const int bid = blockIdx.x, t = threadIdx.x;
    if (bid >= 512) {
        if (bid < 560) {
            // transpose enc_w (384x192) -> WEG rows [0,192)
            const int h0 = (bid - 512) * 4;
            V4<F32> w; w.load(enc_w, (size_t)t * HID + h0);
            #pragma unroll
            for (int j = 0; j < 4; j++) WEG[(size_t)(h0 + j) * 384 + t] = w.g(j);
        } else {
            // copy/convert dec_w (192x384) -> WEG rows [192,384)
            const int r0 = (bid - 560) * 4;
            #pragma unroll
            for (int j = 0; j < 4; j++)
                WEG[(size_t)(192 + r0 + j) * 384 + t] =
                    ldg<F32>(dec_w, (size_t)(r0 + j) * ZDIM + t);
        }
        return;
    }
    float* xs = S;            // 8 x 384
    float* part = S + 3072;   // 16 x 768
    const int rowg = bid >> 3, colt = bid & 7;   // colt fixed per XCD -> L2 slice locality
    const int rb = rowg * 8;
    {
        const int r = t / 48, c8 = 8 * (t % 48);
        float xv[8]; load8<F32>(x, (size_t)(rb + r) * FEAT + c8, xv);
        #pragma unroll
        for (int j = 0; j < 8; j++) xs[r * 384 + c8 + j] = xv[j];
    }
    __syncthreads();
    float out2[2];
    tile_gemm_8x96<F32>(U_w, FFN, colt * 96, xs, part, out2);
    const int uhalf = (colt >= 4);
    float* dst = uhalf ? z0 : xh;
    const int cbase = colt * 96 - (uhalf ? 384 : 0);
    #pragma unroll
    for (int s = 0; s < 2; s++) {
        const int u = t + 384 * s;
        const int m = u / 96, col = u % 96;
        const float v = out2[s] + ldg<F32>(U_b, colt * 96 + col);
        dst[(size_t)(rb + m) * 384 + cbase + col] = gelu_exact(v);
    }
}

// ============ stage 2, z-path: LN -> E,G -> diag/d0 partials ============
// diag[r] = sum_h gelu(E[r,h]+enc_b[h]) * G[r,h] + dec_b . zn_r
// d0[r]   = sum_h gelu(enc_b[h])        * G[r,h] + dec_b . zn_r
template<bool F32>
__device__ void stage2z_body(const void* __restrict__ ln_w, const void* __restrict__ ln_b,
                             const void* __restrict__ enc_b, const void* __restrict__ dec_b,
                             const float* __restrict__ z0, const float* __restrict__ WEG,
                             float* __restrict__ d0p, float* __restrict__ dgp,
                             float* S, int q)
{
    const int rowg = q >> 2, ht = q & 3;
    const int rb = rowg * 8, h0 = ht * 48;
    const int t = threadIdx.x;
    float* zs  = S;          // 8 x 384
    float* pEG = S + 3072;   // 4 x 768
    float* Es  = S + 6144;   // 8 x 48
    float* Gs  = S + 6528;   // 8 x 48
    float* sm  = S + 6912;   // 96

    const int r = t / 48, c8 = 8 * (t % 48);
    float zv[8];
    {
        const float4 a = *(const float4*)(z0 + (size_t)(rb + r) * 384 + c8);
        const float4 b = *(const float4*)(z0 + (size_t)(rb + r) * 384 + c8 + 4);
        zv[0]=a.x;zv[1]=a.y;zv[2]=a.z;zv[3]=a.w;zv[4]=b.x;zv[5]=b.y;zv[6]=b.z;zv[7]=b.w;
    }
    float s1 = 0.f, s2 = 0.f;
    #pragma unroll
    for (int j = 0; j < 8; j++) { s1 += zv[j]; s2 += zv[j] * zv[j]; }
    float sv[16] = {}; sv[r] = s1; sv[8 + r] = s2;
    float SS[16];
    block_sum16(sv, sm, SS);
    const float mu = SS[r] * (1.0f / ZDIM);
    const float rs = rsqrtf(SS[8 + r] * (1.0f / ZDIM) - mu * mu + 1e-5f);
    float lw[8], lb[8];
    load8<F32>(ln_w, c8, lw);
    load8<F32>(ln_b, c8, lb);
    #pragma unroll
    for (int j = 0; j < 8; j++)
        zs[r * 384 + c8 + j] = (zv[j] - mu) * rs * lw[j] + lb[j];
    __syncthreads();

    // E/G GEMM: hg<48 -> E col (WEG row h0+hg); hg>=48 -> G col (WEG row 192+h0+hg-48)
    const int hg = t % 96, kh = t / 96;              // kh<4, K-chunk 96
    const int wrow = h0 + hg + (hg < 48 ? 0 : 144);
    const float* Wr = WEG + (size_t)wrow * 384 + kh * 96;
    float acc[8] = {};
    float4 wb[2][4];
    #pragma unroll
    for (int j = 0; j < 4; j++) wb[0][j] = *(const float4*)(Wr + 4 * j);
    #pragma unroll
    for (int g = 0; g < 6; g++) {
        const int cur = g & 1;
        if (g < 5) {
            #pragma unroll
            for (int j = 0; j < 4; j++)
                wb[cur ^ 1][j] = *(const float4*)(Wr + 16 * (g + 1) + 4 * j);
        }
        #pragma unroll
        for (int j = 0; j < 4; j++) {
            const int k = kh * 96 + 16 * g + 4 * j;
            const float4 wq = wb[cur][j];
            #pragma unroll
            for (int rr = 0; rr < 8; rr++) {
                const float4 zq = *(const float4*)(zs + rr * 384 + k);
                acc[rr] = fmaf(zq.x, wq.x, fmaf(zq.y, wq.y,
                          fmaf(zq.z, wq.z, fmaf(zq.w, wq.w, acc[rr]))));
            }
        }
    }
    #pragma unroll
    for (int rr = 0; rr < 8; rr++) pEG[kh * 768 + rr * 96 + hg] = acc[rr];
    __syncthreads();
    #pragma unroll
    for (int s = 0; s < 2; s++) {
        const int u = t + 384 * s;
        const int ur = u / 96, uh = u % 96;
        const float v = pEG[u] + pEG[768 + u] + pEG[1536 + u] + pEG[2304 + u];
        if (uh < 48) Es[ur * 48 + uh] = v + ldg<F32>(enc_b, h0 + uh);
        else         Gs[ur * 48 + uh - 48] = v;
    }
    __syncthreads();
    const int pr = t / 48, ph = t % 48;
    const float gv = Gs[pr * 48 + ph];
    float pd = gelu_exact(Es[pr * 48 + ph]) * gv;
    float p0 = gelu_exact(ldg<F32>(enc_b, h0 + ph)) * gv;
    if (ht == 0) {
        float dbz = 0.f;
        #pragma unroll
        for (int j = 0; j < 8; j++) {
            const int c = ph + 48 * j;
            dbz = fmaf(ldg<F32>(dec_b, c), zs[pr * 384 + c], dbz);
        }
        pd += dbz; p0 += dbz;
    }
    float sv2[16] = {}; sv2[pr] = pd; sv2[8 + pr] = p0;
    float SS2[16];
    block_sum16(sv2, sm, SS2);
    if (t < 8)            dgp[ht * BN + rb + t] = SS2[t];
    else if (t < 16)      d0p[ht * BN + rb + (t - 8)] = SS2[8 + (t - 8)];
}

// ============ stage 2, Y-path: Y = xh @ V_w ============
template<bool F32>
__device__ void stage2y_body(const void* __restrict__ V_w, const float* __restrict__ xh,
                             float* __restrict__ Y, float* S, int q)
{
    const int rowg = q >> 2, colt = q & 3;
    const int rb = rowg * 8, c0 = colt * 96;
    const int t = threadIdx.x;
    float* xs = S;
    float* part = S + 3072;
    {
        const int r = t / 48, c8 = 8 * (t % 48);
        const float4 a = *(const float4*)(xh + (size_t)(rb + r) * 384 + c8);
        const float4 b = *(const float4*)(xh + (size_t)(rb + r) * 384 + c8 + 4);
        *(float4*)(xs + r * 384 + c8) = a;
        *(float4*)(xs + r * 384 + c8 + 4) = b;
    }
    __syncthreads();
    float out2[2];
    tile_gemm_8x96<F32>(V_w, FEAT, c0, xs, part, out2);
    #pragma unroll
    for (int s = 0; s < 2; s++) {
        const int u = t + 384 * s;
        const int m = u / 96, col = u % 96;
        Y[(size_t)(rb + m) * 384 + c0 + col] = out2[s];
    }
}

__global__ __launch_bounds__(384, 3) void k_stage1(
    const void* x, const void* U_w, const void* U_b, const void* ln_w,
    const void* enc_w, const void* dec_w,
    float* xh, float* z0, float* WEG)
{
    __shared__ float S[S_LDS];
    if (is_f32(ln_w)) stage1_body<true >(x, U_w, U_b, enc_w, dec_w, xh, z0, WEG, S);
    else              stage1_body<false>(x, U_w, U_b, enc_w, dec_w, xh, z0, WEG, S);
}

__global__ __launch_bounds__(384, 3) void k_stage2(
    const void* ln_w, const void* ln_b, const void* enc_b, const void* dec_b,
    const void* V_w, const float* xh, const float* z0, const float* WEG,
    float* Y, float* d0p, float* dgp)
{
    __shared__ float S[S_LDS];
    // type split at bid 256 so each CU gets one z-path and one Y-path block
    const int type = blockIdx.x >> 8;
    const int q = blockIdx.x & 255;
    if (is_f32(ln_w)) {
        if (type == 0) stage2z_body<true >(ln_w, ln_b, enc_b, dec_b, z0, WEG, d0p, dgp, S, q);
        else           stage2y_body<true >(V_w, xh, Y, S, q);
    } else {
        if (type == 0) stage2z_body<false>(ln_w, ln_b, enc_b, dec_b, z0, WEG, d0p, dgp, S, q);
        else           stage2y_body<false>(V_w, xh, Y, S, q);
    }
}

// ============ combine: 64 blocks = 4 batches x 16 col-chunks of 24 ============
template<bool F32>
__device__ void combine_body(
    const float* __restrict__ d0p, const float* __restrict__ dgp,
    const float* __restrict__ Y,
    const void* __restrict__ V_b, void* __restrict__ out)
{
    const int b  = blockIdx.x >> 4;
    const int cc = (blockIdx.x & 15) * 24;
    const int t = threadIdx.x;
    const int c = t % 24, qq = t / 24;      // 16 row-groups of 8 rows
    __shared__ float e0s[NN], eds[NN];
    __shared__ float bp[16 * 24];
    __shared__ float baseY[24];
    __shared__ float sm[12];

    float d0v = -INFINITY, dgv = -INFINITY;
    if (t < NN) {
        float a0 = 0.f, ag = 0.f;
        #pragma unroll
        for (int ct = 0; ct < 4; ct++) {
            a0 += d0p[ct * BN + b * NN + t];
            ag += dgp[ct * BN + b * NN + t];
        }
        d0v = a0; dgv = ag;
    }
    const float m = block_max(fmaxf(d0v, dgv), sm);
    float e0v = 0.f;
    if (t < NN) {
        e0v = expf(d0v - m);
        e0s[t] = e0v;
        eds[t] = expf(dgv - m);
    }
    const float Ssum = block_sum(e0v, sm);     // internal syncs publish e0s/eds

    const float* Yb = Y + (size_t)b * NN * FEAT + cc + c;
    const int j0 = 8 * qq;
    float w[8];
    #pragma unroll
    for (int j = 0; j < 8; j++) w[j] = Yb[(size_t)(j0 + j) * FEAT];
    float p = 0.f;
    #pragma unroll
    for (int j = 0; j < 8; j++) p = fmaf(e0s[j0 + j], w[j], p);
    bp[qq * 24 + c] = p;
    __syncthreads();
    if (qq == 0) {
        float s = 0.f;
        #pragma unroll
        for (int g = 0; g < 16; g++) s += bp[g * 24 + c];
        baseY[c] = s;
    }
    __syncthreads();

    const float bY = baseY[c];
    const float vb = ldg<F32>(V_b, cc + c);
    #pragma unroll
    for (int j = 0; j < 8; j++) {
        const int r = j0 + j;
        const float inv = 1.0f / (Ssum - e0s[r] + eds[r]);
        const float val = (bY + (eds[r] - e0s[r]) * w[j]) * inv + vb;
        stg<F32>(out, (size_t)(b * NN + r) * FEAT + cc + c, val);
    }
}

__global__ __launch_bounds__(384) void k_combine(
    const void* ln_w,
    const float* d0p, const float* dgp, const float* Y,
    const void* V_b, void* out)
{
    if (is_f32(ln_w))
        combine_body<true >(d0p, dgp, Y, V_b, out);
    else
        combine_body<false>(d0p, dgp, Y, V_b, out);
}

extern "C" void kernel_launch(void* const* d_in, const int* in_sizes, int n_in,
                              void* d_out, int out_size, void* d_ws, size_t ws_size,
                              hipStream_t stream) {
    const void* x     = d_in[0];
    const void* U_w   = d_in[1];
    const void* U_b   = d_in[2];
    const void* ln_w  = d_in[3];
    const void* ln_b  = d_in[4];
    const void* enc_w = d_in[5];
    const void* enc_b = d_in[6];
    const void* dec_w = d_in[7];
    const void* dec_b = d_in[8];
    const void* V_w   = d_in[9];
    const void* V_b   = d_in[10];

    float* ws  = (float*)d_ws;
    float* xh  = ws;                 // 512*384
    float* z0  = xh  + 196608;       // 512*384 (post-gelu, pre-LN)
    float* WEG = z0  + 196608;       // 384*384 fp32: [enc_w^T ; dec_w]
    float* Y   = WEG + 147456;       // 512*384
    float* d0p = Y   + 196608;       // 4*512
    float* dgp = d0p + 4 * BN;       // 4*512

    k_stage1<<<608, 384, 0, stream>>>(x, U_w, U_b, ln_w, enc_w, dec_w, xh, z0, WEG);
    k_stage2<<<512, 384, 0, stream>>>(ln_w, ln_b, enc_b, dec_b, V_w, xh, z0, WEG, Y, d0p, dgp);
    k_combine<<<16 * BB, 384, 0, stream>>>(ln_w, d0p, dgp, Y, V_b, d_out);
}